// Round 6
// baseline (425.090 us; speedup 1.0000x reference)
//
#include <hip/hip_runtime.h>
#include <hip/hip_bf16.h>

typedef unsigned short u16;
typedef unsigned int u32;
typedef short bf16x8 __attribute__((ext_vector_type(8)));
typedef float f32x4 __attribute__((ext_vector_type(4)));

__device__ inline float bf2f(u16 u) { return __uint_as_float(((u32)u) << 16); }
__device__ inline u16 f2bf(float f) {
    u32 x = __float_as_uint(f);
    return (u16)((x + 0x7FFFu + ((x >> 16) & 1u)) >> 16);  // RNE
}

// ---------------- Kernel 1: Wh_t[b][f][j] = (x @ W)^T (bf16) + fused colsum S ----------------
// (byte-identical since round 3)
__global__ __launch_bounds__(256) void k_gemm1(const float* __restrict__ x,
                                               const float* __restrict__ W,
                                               u16* __restrict__ Wht,
                                               float* __restrict__ S) {
    __shared__ __align__(16) u16 Wt[128][136];
    const int t = threadIdx.x;
    {
        int k = t >> 1;
        int f0 = (t & 1) * 64;
        const float4* wp = reinterpret_cast<const float4*>(W + k * 128 + f0);
#pragma unroll
        for (int q = 0; q < 16; ++q) {
            float4 v = wp[q];
            int f = f0 + q * 4;
            Wt[f + 0][k] = f2bf(v.x);
            Wt[f + 1][k] = f2bf(v.y);
            Wt[f + 2][k] = f2bf(v.z);
            Wt[f + 3][k] = f2bf(v.w);
        }
    }
    __syncthreads();

    const int w = t >> 6, l = t & 63;
    const int lr = l & 15, lg = l >> 4;
    const int fh = (w & 1) * 64;
    const int jh = (w >> 1) * 64;
    const int j0 = blockIdx.x * 128;

    f32x4 acc[4][4];
#pragma unroll
    for (int m = 0; m < 4; ++m)
#pragma unroll
        for (int n = 0; n < 4; ++n) acc[m][n] = (f32x4){0.f, 0.f, 0.f, 0.f};

#pragma unroll
    for (int ks = 0; ks < 4; ++ks) {
        bf16x8 a[4], bb[4];
#pragma unroll
        for (int m = 0; m < 4; ++m)
            a[m] = *reinterpret_cast<const bf16x8*>(&Wt[fh + m * 16 + lr][ks * 32 + lg * 8]);
#pragma unroll
        for (int n = 0; n < 4; ++n) {
            int j = j0 + jh + n * 16 + lr;
            const float* xp = x + (size_t)j * 128 + ks * 32 + lg * 8;
            float4 v0 = *reinterpret_cast<const float4*>(xp);
            float4 v1 = *reinterpret_cast<const float4*>(xp + 4);
            bf16x8 bv;
            bv[0] = (short)f2bf(v0.x); bv[1] = (short)f2bf(v0.y);
            bv[2] = (short)f2bf(v0.z); bv[3] = (short)f2bf(v0.w);
            bv[4] = (short)f2bf(v1.x); bv[5] = (short)f2bf(v1.y);
            bv[6] = (short)f2bf(v1.z); bv[7] = (short)f2bf(v1.w);
            bb[n] = bv;
        }
#pragma unroll
        for (int m = 0; m < 4; ++m)
#pragma unroll
            for (int n = 0; n < 4; ++n)
                acc[m][n] = __builtin_amdgcn_mfma_f32_16x16x32_bf16(a[m], bb[n], acc[m][n], 0, 0, 0);
    }

    const int bb_ = blockIdx.x >> 5;
    const int jj = (blockIdx.x & 31) * 128;
    u16* base = Wht + ((size_t)bb_ << 19);
    float* Sb = S + bb_ * 128;
#pragma unroll
    for (int m = 0; m < 4; ++m) {
        int f = fh + m * 16 + lg * 4;
#pragma unroll
        for (int n = 0; n < 4; ++n) {
            int j = jj + jh + n * 16 + lr;
#pragma unroll
            for (int r = 0; r < 4; ++r)
                base[(size_t)(f + r) * 4096 + j] = f2bf(acc[m][n][r]);
        }
#pragma unroll
        for (int r = 0; r < 4; ++r) {
            float sj = 0.f;
#pragma unroll
            for (int n = 0; n < 4; ++n) sj += acc[m][n][r];
            sj += __shfl_xor(sj, 1);
            sj += __shfl_xor(sj, 2);
            sj += __shfl_xor(sj, 4);
            sj += __shfl_xor(sj, 8);
            if (lr == 0) atomicAdd(&Sb[f + r], sj);
        }
    }
}

// ---------------- Kernel 2: partial[ksp][b][i][f] = sum_{j in quarter: adj>0} Wh[b][j][f] ----------------
// BM=64, K-split 4 -> grid 1024 = 4 blocks/CU (16 waves/CU) for latency hiding.
// A (adj) via LDS double-buffer with reg prefetch; B (Wh_t, L2-resident panel)
// gathered global->reg, no LDS, no barrier.
__global__ __launch_bounds__(256, 4) void k_gemm2(const int* __restrict__ adj,
                                                  const u16* __restrict__ Wht,
                                                  float* __restrict__ part,   // [4][4][4096][128]
                                                  int* __restrict__ cnt) {    // [4*4096]
    __shared__ __align__(16) u16 As[2][64][72];  // +8 pad

    const int t = threadIdx.x;
    // XCD-bijective swizzle (1024 % 8 == 0): XCD x gets swz in [128x, 128x+127]
    // = half a batch (2 ksp panels x 64 i-blocks) -> 512 KB Wh_t L2-resident.
    const int raw = blockIdx.x;
    const int swz = (raw & 7) * 128 + (raw >> 3);
    const int b   = swz >> 8;
    const int rem = swz & 255;
    const int ksp = rem >> 6;
    const int i0  = (rem & 63) * 64;
    const int koff = ksp * 1024;

    const int* adjb = adj + ((size_t)b << 24) + (size_t)i0 * 4096 + koff;
    const u16* whb  = Wht + ((size_t)b << 19) + koff;

    // A staging: 4 threads per row, 16 ints each
    const int ai = t >> 2;
    const int aq = t & 3;
    const int* aptr = adjb + (size_t)ai * 4096 + aq * 16;

    int4 av[4];
    int cntv = 0;

    auto issueA = [&](int kt) {
        const int4* p = reinterpret_cast<const int4*>(aptr + kt * 64);
        av[0] = p[0]; av[1] = p[1]; av[2] = p[2]; av[3] = p[3];
    };
    auto convertA = [&](int buf) {
        u32 u[8];
#pragma unroll
        for (int q = 0; q < 4; ++q) {
            int4 v = av[q];
            cntv += (v.x > 0) + (v.y > 0) + (v.z > 0) + (v.w > 0);
            u[q * 2 + 0] = ((v.x > 0) ? 0x3F80u : 0u) | (((v.y > 0) ? 0x3F80u : 0u) << 16);
            u[q * 2 + 1] = ((v.z > 0) ? 0x3F80u : 0u) | (((v.w > 0) ? 0x3F80u : 0u) << 16);
        }
        *reinterpret_cast<uint4*>(&As[buf][ai][aq * 16]) = make_uint4(u[0], u[1], u[2], u[3]);
        *reinterpret_cast<uint4*>(&As[buf][ai][aq * 16 + 8]) = make_uint4(u[4], u[5], u[6], u[7]);
    };

    const int w = t >> 6, l = t & 63;
    const int lr = l & 15, lg = l >> 4;
    const int ir0 = (w & 1) * 2;   // 2 i-frags per wave
    const int fr0 = (w >> 1) * 4;  // 4 f-frags per wave

    const u16* bptr0 = whb + (size_t)((fr0 + 0) * 16 + lr) * 4096 + lg * 8;
    const u16* bptr1 = whb + (size_t)((fr0 + 1) * 16 + lr) * 4096 + lg * 8;
    const u16* bptr2 = whb + (size_t)((fr0 + 2) * 16 + lr) * 4096 + lg * 8;
    const u16* bptr3 = whb + (size_t)((fr0 + 3) * 16 + lr) * 4096 + lg * 8;

    f32x4 acc[2][4];
#pragma unroll
    for (int m = 0; m < 2; ++m)
#pragma unroll
        for (int n = 0; n < 4; ++n) acc[m][n] = (f32x4){0.f, 0.f, 0.f, 0.f};

    issueA(0);
    convertA(0);
    __syncthreads();

    for (int kt = 0; kt < 16; ++kt) {
        const int cur = kt & 1;
        // B gather first so MFMA's vmcnt wait leaves the A prefetch in flight
        bf16x8 bb0[4], bb1[4];
        bb0[0] = *reinterpret_cast<const bf16x8*>(bptr0 + kt * 64);
        bb0[1] = *reinterpret_cast<const bf16x8*>(bptr1 + kt * 64);
        bb0[2] = *reinterpret_cast<const bf16x8*>(bptr2 + kt * 64);
        bb0[3] = *reinterpret_cast<const bf16x8*>(bptr3 + kt * 64);
        bb1[0] = *reinterpret_cast<const bf16x8*>(bptr0 + kt * 64 + 32);
        bb1[1] = *reinterpret_cast<const bf16x8*>(bptr1 + kt * 64 + 32);
        bb1[2] = *reinterpret_cast<const bf16x8*>(bptr2 + kt * 64 + 32);
        bb1[3] = *reinterpret_cast<const bf16x8*>(bptr3 + kt * 64 + 32);
        if (kt + 1 < 16) issueA(kt + 1);  // reg prefetch of next adj tile

#pragma unroll
        for (int ks = 0; ks < 2; ++ks) {
            bf16x8 a0 = *reinterpret_cast<const bf16x8*>(&As[cur][(ir0 + 0) * 16 + lr][ks * 32 + lg * 8]);
            bf16x8 a1 = *reinterpret_cast<const bf16x8*>(&As[cur][(ir0 + 1) * 16 + lr][ks * 32 + lg * 8]);
#pragma unroll
            for (int n = 0; n < 4; ++n) {
                bf16x8 bv = ks ? bb1[n] : bb0[n];
                acc[0][n] = __builtin_amdgcn_mfma_f32_16x16x32_bf16(a0, bv, acc[0][n], 0, 0, 0);
                acc[1][n] = __builtin_amdgcn_mfma_f32_16x16x32_bf16(a1, bv, acc[1][n], 0, 0, 0);
            }
        }

        if (kt + 1 < 16) convertA(cur ^ 1);
        __syncthreads();
    }

    // per-row count for this K-quarter
    int c = cntv + __shfl_xor(cntv, 1);
    c += __shfl_xor(c, 2);
    if ((t & 3) == 0) atomicAdd(&cnt[b * 4096 + i0 + ai], c);

    // store partial sums (f32, coalesced over f)
    float* pb = part + ((size_t)ksp << 21) + ((size_t)b * 4096 + i0) * 128;
#pragma unroll
    for (int m = 0; m < 2; ++m) {
#pragma unroll
        for (int n = 0; n < 4; ++n) {
            int f = (fr0 + n) * 16 + lr;
#pragma unroll
            for (int r = 0; r < 4; ++r) {
                int il = (ir0 + m) * 16 + lg * 4 + r;
                pb[(size_t)il * 128 + f] = acc[m][n][r];
            }
        }
    }
}

// ---------------- Kernel 3: out = (sum_k part_k)/cnt, empty-row fallback ----------------
__global__ __launch_bounds__(256) void k_fin(const float* __restrict__ part,
                                             const int* __restrict__ cnt,
                                             const float* __restrict__ S,
                                             float* __restrict__ out) {
    int e = blockIdx.x * 256 + threadIdx.x;  // 2M elements
    int f = e & 127;
    int row = e >> 7;      // b*4096 + i
    int b = row >> 12;
    int c = cnt[row];
    float p = part[e] + part[e + (1 << 21)] + part[e + (2 << 21)] + part[e + (3 << 21)];
    float v;
    if (c > 0) v = p / (float)c;
    else       v = S[b * 128 + f] * (1.0f / 4096.0f);  // uniform softmax over all-masked row
    out[e] = v;
}

extern "C" void kernel_launch(void* const* d_in, const int* in_sizes, int n_in,
                              void* d_out, int out_size, void* d_ws, size_t ws_size,
                              hipStream_t stream) {
    const float* x = (const float*)d_in[0];
    const int* adj = (const int*)d_in[1];
    const float* W = (const float*)d_in[2];
    // d_in[3] (a) is mathematically dead: softmax of a j-constant over the adj
    // support is uniform, so attention = adj / rowsum(adj).
    float* out = (float*)d_out;

    char* wsb = (char*)d_ws;
    float* S    = (float*)(wsb);                   // 512 f32 (2 KB)
    int*   cnt  = (int*)(wsb + 4096);              // 16384 i32 (64 KB)
    float* part = (float*)(wsb + (1u << 20));      // 4 x 8 MB f32 partials
    u16*   Wht  = (u16*)(wsb + (40u << 20));       // 4 MB bf16

    hipMemsetAsync(wsb, 0, 4096 + 65536, stream);  // zero S + cnt
    k_gemm1<<<128, 256, 0, stream>>>(x, W, Wht, S);
    k_gemm2<<<1024, 256, 0, stream>>>(adj, Wht, part, cnt);
    k_fin<<<8192, 256, 0, stream>>>(part, cnt, S, out);
}

// Round 8
// 413.697 us; speedup vs baseline: 1.0275x; 1.0275x over previous
//
#include <hip/hip_runtime.h>
#include <hip/hip_bf16.h>

typedef unsigned short u16;
typedef unsigned int u32;
typedef short bf16x8 __attribute__((ext_vector_type(8)));
typedef float f32x4 __attribute__((ext_vector_type(4)));

__device__ inline float bf2f(u16 u) { return __uint_as_float(((u32)u) << 16); }
__device__ inline u16 f2bf(float f) {
    u32 x = __float_as_uint(f);
    return (u16)((x + 0x7FFFu + ((x >> 16) & 1u)) >> 16);  // RNE
}

// ---------------- Kernel 1: Wh_t[b][f][j] = (x @ W)^T (bf16) + fused colsum S ----------------
// (byte-identical since round 3)
__global__ __launch_bounds__(256) void k_gemm1(const float* __restrict__ x,
                                               const float* __restrict__ W,
                                               u16* __restrict__ Wht,
                                               float* __restrict__ S) {
    __shared__ __align__(16) u16 Wt[128][136];
    const int t = threadIdx.x;
    {
        int k = t >> 1;
        int f0 = (t & 1) * 64;
        const float4* wp = reinterpret_cast<const float4*>(W + k * 128 + f0);
#pragma unroll
        for (int q = 0; q < 16; ++q) {
            float4 v = wp[q];
            int f = f0 + q * 4;
            Wt[f + 0][k] = f2bf(v.x);
            Wt[f + 1][k] = f2bf(v.y);
            Wt[f + 2][k] = f2bf(v.z);
            Wt[f + 3][k] = f2bf(v.w);
        }
    }
    __syncthreads();

    const int w = t >> 6, l = t & 63;
    const int lr = l & 15, lg = l >> 4;
    const int fh = (w & 1) * 64;
    const int jh = (w >> 1) * 64;
    const int j0 = blockIdx.x * 128;

    f32x4 acc[4][4];
#pragma unroll
    for (int m = 0; m < 4; ++m)
#pragma unroll
        for (int n = 0; n < 4; ++n) acc[m][n] = (f32x4){0.f, 0.f, 0.f, 0.f};

#pragma unroll
    for (int ks = 0; ks < 4; ++ks) {
        bf16x8 a[4], bb[4];
#pragma unroll
        for (int m = 0; m < 4; ++m)
            a[m] = *reinterpret_cast<const bf16x8*>(&Wt[fh + m * 16 + lr][ks * 32 + lg * 8]);
#pragma unroll
        for (int n = 0; n < 4; ++n) {
            int j = j0 + jh + n * 16 + lr;
            const float* xp = x + (size_t)j * 128 + ks * 32 + lg * 8;
            float4 v0 = *reinterpret_cast<const float4*>(xp);
            float4 v1 = *reinterpret_cast<const float4*>(xp + 4);
            bf16x8 bv;
            bv[0] = (short)f2bf(v0.x); bv[1] = (short)f2bf(v0.y);
            bv[2] = (short)f2bf(v0.z); bv[3] = (short)f2bf(v0.w);
            bv[4] = (short)f2bf(v1.x); bv[5] = (short)f2bf(v1.y);
            bv[6] = (short)f2bf(v1.z); bv[7] = (short)f2bf(v1.w);
            bb[n] = bv;
        }
#pragma unroll
        for (int m = 0; m < 4; ++m)
#pragma unroll
            for (int n = 0; n < 4; ++n)
                acc[m][n] = __builtin_amdgcn_mfma_f32_16x16x32_bf16(a[m], bb[n], acc[m][n], 0, 0, 0);
    }

    const int bb_ = blockIdx.x >> 5;
    const int jj = (blockIdx.x & 31) * 128;
    u16* base = Wht + ((size_t)bb_ << 19);
    float* Sb = S + bb_ * 128;
#pragma unroll
    for (int m = 0; m < 4; ++m) {
        int f = fh + m * 16 + lg * 4;
#pragma unroll
        for (int n = 0; n < 4; ++n) {
            int j = jj + jh + n * 16 + lr;
#pragma unroll
            for (int r = 0; r < 4; ++r)
                base[(size_t)(f + r) * 4096 + j] = f2bf(acc[m][n][r]);
        }
#pragma unroll
        for (int r = 0; r < 4; ++r) {
            float sj = 0.f;
#pragma unroll
            for (int n = 0; n < 4; ++n) sj += acc[m][n][r];
            sj += __shfl_xor(sj, 1);
            sj += __shfl_xor(sj, 2);
            sj += __shfl_xor(sj, 4);
            sj += __shfl_xor(sj, 8);
            if (lr == 0) atomicAdd(&Sb[f + r], sj);
        }
    }
}

// ---------------- Kernel 2: partial[ksp][b][i][f] = sum_{j in half: adj>0} Wh[b][j][f] ----------------
// BM=64, K-split 2, grid 512 (2 blocks/CU). Software-pipelined: A (adj) reg-prefetch
// depth ~1.5 steps -> LDS double-buffer; B (Wh_t, L2 panel) reg double-buffer.
// Raw s_barrier + lgkmcnt(0) only: global prefetches stay in flight across barriers
// (compiler emits counted vmcnt from reg deps), removing the per-step vmcnt(0) drain.
__global__ __launch_bounds__(256, 2) void k_gemm2(const int* __restrict__ adj,
                                                  const u16* __restrict__ Wht,
                                                  float* __restrict__ part,   // [2][4][4096][128]
                                                  int* __restrict__ cnt) {    // [4*4096]
    __shared__ __align__(16) u16 As[2][64][72];  // +8 pad

    const int t = threadIdx.x;
    const int raw = blockIdx.x;
    const int swz = (raw & 7) * 64 + (raw >> 3);  // XCD-bijective: 1 (b,ksp) panel per XCD
    const int b   = swz >> 7;
    const int ksp = (swz >> 6) & 1;
    const int i0  = (swz & 63) * 64;
    const int koff = ksp * 2048;

    const int* adjb = adj + ((size_t)b << 24) + (size_t)i0 * 4096 + koff;
    const u16* whb  = Wht + ((size_t)b << 19) + koff;

    const int ai = t >> 2;
    const int aq = t & 3;
    const int* aptr = adjb + (size_t)ai * 4096 + aq * 16;

    int cntv = 0;
    int4 av[2][4];           // A reg double-buffer (parity-static indexing only)
    bf16x8 Bk0[2][4], Bk1[2][4];  // B reg double-buffer

    const int w = t >> 6, l = t & 63;
    const int lr = l & 15, lg = l >> 4;
    const int ir0 = (w & 1) * 2;
    const int fr0 = (w >> 1) * 4;

    const u16* bp[4];
#pragma unroll
    for (int n = 0; n < 4; ++n)
        bp[n] = whb + (size_t)((fr0 + n) * 16 + lr) * 4096 + lg * 8;

#define ISSUE_A(P, KT)                                                              \
    {                                                                               \
        const int4* _p = reinterpret_cast<const int4*>(aptr + (KT) * 64);           \
        av[P][0] = _p[0]; av[P][1] = _p[1]; av[P][2] = _p[2]; av[P][3] = _p[3];     \
    }
#define ISSUE_B(P, KT)                                                              \
    {                                                                               \
        _Pragma("unroll")                                                           \
        for (int n = 0; n < 4; ++n) {                                               \
            Bk0[P][n] = *reinterpret_cast<const bf16x8*>(bp[n] + (KT) * 64);        \
            Bk1[P][n] = *reinterpret_cast<const bf16x8*>(bp[n] + (KT) * 64 + 32);   \
        }                                                                           \
    }
#define CONVERT_A(P)                                                                \
    {                                                                               \
        u32 u[8];                                                                   \
        _Pragma("unroll")                                                           \
        for (int q = 0; q < 4; ++q) {                                               \
            int4 v = av[P][q];                                                      \
            cntv += (v.x > 0) + (v.y > 0) + (v.z > 0) + (v.w > 0);                  \
            u[q * 2 + 0] = ((v.x > 0) ? 0x3F80u : 0u) | (((v.y > 0) ? 0x3F80u : 0u) << 16); \
            u[q * 2 + 1] = ((v.z > 0) ? 0x3F80u : 0u) | (((v.w > 0) ? 0x3F80u : 0u) << 16); \
        }                                                                           \
        *reinterpret_cast<uint4*>(&As[P][ai][aq * 16]) = make_uint4(u[0], u[1], u[2], u[3]); \
        *reinterpret_cast<uint4*>(&As[P][ai][aq * 16 + 8]) = make_uint4(u[4], u[5], u[6], u[7]); \
    }
#define BARRIER()                                                                   \
    {                                                                               \
        asm volatile("s_waitcnt lgkmcnt(0)" ::: "memory");                          \
        __builtin_amdgcn_sched_barrier(0);                                          \
        __builtin_amdgcn_s_barrier();                                               \
    }
#define MFMA_STEP(P)                                                                \
    {                                                                               \
        _Pragma("unroll")                                                           \
        for (int ks = 0; ks < 2; ++ks) {                                            \
            bf16x8 a0 = *reinterpret_cast<const bf16x8*>(&As[P][(ir0 + 0) * 16 + lr][ks * 32 + lg * 8]); \
            bf16x8 a1 = *reinterpret_cast<const bf16x8*>(&As[P][(ir0 + 1) * 16 + lr][ks * 32 + lg * 8]); \
            _Pragma("unroll")                                                       \
            for (int n = 0; n < 4; ++n) {                                           \
                bf16x8 bv = ks ? Bk1[P][n] : Bk0[P][n];                             \
                acc[0][n] = __builtin_amdgcn_mfma_f32_16x16x32_bf16(a0, bv, acc[0][n], 0, 0, 0); \
                acc[1][n] = __builtin_amdgcn_mfma_f32_16x16x32_bf16(a1, bv, acc[1][n], 0, 0, 0); \
            }                                                                       \
        }                                                                           \
    }

    f32x4 acc[2][4];
#pragma unroll
    for (int m = 0; m < 2; ++m)
#pragma unroll
        for (int n = 0; n < 4; ++n) acc[m][n] = (f32x4){0.f, 0.f, 0.f, 0.f};

    // prologue: tiles 0,1 in regs; tile0 -> LDS[0]; B(0) in regs
    ISSUE_A(0, 0);
    ISSUE_A(1, 1);
    CONVERT_A(0);           // waits A(0) only (A(1) stays in flight)
    ISSUE_B(0, 0);
    BARRIER();

    // steady state: step kt (parity P): issueA(kt+2)->av[P], issueB(kt+1)->B[P^1],
    // MFMA(LDS[P], B[P]), convert av[P^1]=A(kt+1)->LDS[P^1], barrier.
    for (int kp = 0; kp < 15; ++kp) {
        const int kt0 = kp * 2;
        // parity 0
        ISSUE_A(0, kt0 + 2);
        ISSUE_B(1, kt0 + 1);
        MFMA_STEP(0);
        CONVERT_A(1);
        BARRIER();
        // parity 1
        ISSUE_A(1, kt0 + 3);
        ISSUE_B(0, kt0 + 2);
        MFMA_STEP(1);
        CONVERT_A(0);
        BARRIER();
    }
    // epilogue: steps 30, 31
    ISSUE_B(1, 31);
    MFMA_STEP(0);
    CONVERT_A(1);
    BARRIER();
    MFMA_STEP(1);

#undef ISSUE_A
#undef ISSUE_B
#undef CONVERT_A
#undef BARRIER
#undef MFMA_STEP

    // per-row count for this K-half
    int c = cntv + __shfl_xor(cntv, 1);
    c += __shfl_xor(c, 2);
    if ((t & 3) == 0) atomicAdd(&cnt[b * 4096 + i0 + ai], c);

    // store partial sums (f32, coalesced over f)
    float* pb = part + ((size_t)ksp << 21) + ((size_t)b * 4096 + i0) * 128;
#pragma unroll
    for (int m = 0; m < 2; ++m) {
#pragma unroll
        for (int n = 0; n < 4; ++n) {
            int f = (fr0 + n) * 16 + lr;
#pragma unroll
            for (int r = 0; r < 4; ++r) {
                int il = (ir0 + m) * 16 + lg * 4 + r;
                pb[(size_t)il * 128 + f] = acc[m][n][r];
            }
        }
    }
}

// ---------------- Kernel 3: out = (part0+part1)/cnt, empty-row fallback ----------------
__global__ __launch_bounds__(256) void k_fin(const float* __restrict__ part,
                                             const int* __restrict__ cnt,
                                             const float* __restrict__ S,
                                             float* __restrict__ out) {
    int e = blockIdx.x * 256 + threadIdx.x;  // 2M elements
    int f = e & 127;
    int row = e >> 7;      // b*4096 + i
    int b = row >> 12;
    int c = cnt[row];
    float p = part[e] + part[e + (1 << 21)];
    float v;
    if (c > 0) v = p / (float)c;
    else       v = S[b * 128 + f] * (1.0f / 4096.0f);  // uniform softmax over all-masked row
    out[e] = v;
}

extern "C" void kernel_launch(void* const* d_in, const int* in_sizes, int n_in,
                              void* d_out, int out_size, void* d_ws, size_t ws_size,
                              hipStream_t stream) {
    const float* x = (const float*)d_in[0];
    const int* adj = (const int*)d_in[1];
    const float* W = (const float*)d_in[2];
    // d_in[3] (a) is mathematically dead: softmax of a j-constant over the adj
    // support is uniform, so attention = adj / rowsum(adj).
    float* out = (float*)d_out;

    char* wsb = (char*)d_ws;
    float* S    = (float*)(wsb);                   // 512 f32 (2 KB)
    int*   cnt  = (int*)(wsb + 4096);              // 16384 i32 (64 KB)
    float* part = (float*)(wsb + (1u << 20));      // 2 x 8 MB f32 partials
    u16*   Wht  = (u16*)(wsb + (40u << 20));       // 4 MB bf16

    hipMemsetAsync(wsb, 0, 4096 + 65536, stream);  // zero S + cnt
    k_gemm1<<<128, 256, 0, stream>>>(x, W, Wht, S);
    k_gemm2<<<512, 256, 0, stream>>>(adj, Wht, part, cnt);
    k_fin<<<8192, 256, 0, stream>>>(part, cnt, S, out);
}